// Round 9
// baseline (124.162 us; speedup 1.0000x reference)
//
#include <hip/hip_runtime.h>
#include <math.h>

#define N_SAMP 65536
#define DIM    512
#define NCLS   64
#define KSEL   64
#define SNBIN  4096

// workspace layout (bytes)
#define OFF_COUNTS   0u          // 64 i32
#define OFF_CSUM     256u        // 64*512 f32 -> 131328
#define OFF_CENTERS  131328u     // cenb 64*512 bf16 -> 196864
#define OFF_C2       196864u     // 64 f32 -> 197120
#define OFF_MEANS    197120u     // 128 f32 -> 197632
#define OFF_DONE     197632u     // 1 u32
#define OFF_DIST     262144u     // 64*65536 f32 -> 17039360

typedef __attribute__((ext_vector_type(8))) short bf16x8;
typedef __attribute__((ext_vector_type(4))) float f32x4;

__device__ __forceinline__ unsigned short f2bf_rne(float f) {
  const unsigned u = __float_as_uint(f);
  return (unsigned short)((u + 0x7FFFu + ((u >> 16) & 1u)) >> 16);
}

// ---------------------------------------------------------------- init
__global__ __launch_bounds__(256) void k_init(int* __restrict__ counts,
                                              float* __restrict__ csum,
                                              unsigned* __restrict__ done) {
  const int i = blockIdx.x * 256 + threadIdx.x;
  const int stride = gridDim.x * 256;
  if (i < NCLS) counts[i] = 0;
  if (i == 0) *done = 0u;
  for (int j = i; j < NCLS * DIM; j += stride) csum[j] = 0.f;
}

// ------------------------------------------------- class partial sums (proven R4 form, no xb)
__global__ __launch_bounds__(256) void k_class_sums(const float* __restrict__ x,
                                                    const int* __restrict__ y,
                                                    float* __restrict__ csum,
                                                    int* __restrict__ counts) {
  __shared__ int list[4096];
  __shared__ int lcnt;
  const int c  = blockIdx.x >> 4;
  const int r0 = (blockIdx.x & 15) * 4096;
  const int tid = threadIdx.x;
  if (tid == 0) lcnt = 0;
  __syncthreads();
  for (int i = tid; i < 4096; i += 256) {
    if (y[r0 + i] == c) { int p = atomicAdd(&lcnt, 1); list[p] = r0 + i; }
  }
  __syncthreads();
  const int n = lcnt;
  const int dbase = (tid >> 6) * 128 + (tid & 63) * 2;
  float a0 = 0.f, a1 = 0.f, b0 = 0.f, b1 = 0.f;
  int i = 0;
  for (; i + 2 <= n; i += 2) {
    const float* p0 = x + (size_t)list[i] * DIM + dbase;
    const float* p1 = x + (size_t)list[i + 1] * DIM + dbase;
    a0 += p0[0]; a1 += p0[1];
    b0 += p1[0]; b1 += p1[1];
  }
  if (i < n) { const float* p0 = x + (size_t)list[i] * DIM + dbase; a0 += p0[0]; a1 += p0[1]; }
  a0 += b0; a1 += b1;
  atomicAdd(&csum[c * DIM + dbase], a0);
  atomicAdd(&csum[c * DIM + dbase + 1], a1);
  if (tid == 0) atomicAdd(&counts[c], n);
}

// ------------------------------------------------- finalize centers (bf16) + c2 (f32)
__global__ __launch_bounds__(64) void k_centers(const float* __restrict__ csum,
                                                const int* __restrict__ counts,
                                                unsigned short* __restrict__ cenb,
                                                float* __restrict__ c2) {
  const int c = blockIdx.x, l = threadIdx.x;
  const float inv = 1.0f / (float)counts[c];
  float ss = 0.f;
  #pragma unroll
  for (int j = 0; j < 8; ++j) {
    int d = j * 64 + l;
    float v = csum[c * DIM + d] * inv;
    cenb[c * DIM + d] = f2bf_rne(v);
    ss += v * v;
  }
  #pragma unroll
  for (int o = 32; o; o >>= 1) ss += __shfl_down(ss, o, 64);
  if (l == 0) c2[c] = ss;
}

// ------------------------------------------------- distances via bf16 MFMA, NO LDS
// 512 blocks x 512 threads (8 waves, 16 samples/wave). A-frags (centers) read directly
// from global: per-k-step working set is 4KB and shared by every wave -> L1-resident.
__global__ __launch_bounds__(512, 4) void k_dist_g(const float* __restrict__ x,
                                                   const unsigned short* __restrict__ cenb,
                                                   const float* __restrict__ c2,
                                                   float* __restrict__ dist) {
  const int tid = threadIdx.x;
  const int wave = tid >> 6;
  const int lane = tid & 63;
  const int s0 = blockIdx.x * 128 + wave * 16;
  const int samp = s0 + (lane & 15);
  const int kg = lane >> 4;
  const int arow = lane & 15;

  f32x4 acc[4] = {f32x4{0,0,0,0}, f32x4{0,0,0,0}, f32x4{0,0,0,0}, f32x4{0,0,0,0}};
  float x2 = 0.f;
  const float* __restrict__ xrow = x + (size_t)samp * DIM + kg * 8;
  const unsigned short* __restrict__ crow = cenb + (size_t)arow * DIM + kg * 8;

  #pragma unroll 4
  for (int s = 0; s < 16; ++s) {
    const int k0 = s * 32;
    float xf[8];
    *reinterpret_cast<float4*>(&xf[0]) = *reinterpret_cast<const float4*>(xrow + k0);
    *reinterpret_cast<float4*>(&xf[4]) = *reinterpret_cast<const float4*>(xrow + k0 + 4);
    const bf16x8 a0 = *reinterpret_cast<const bf16x8*>(crow + k0);
    const bf16x8 a1 = *reinterpret_cast<const bf16x8*>(crow + 16 * DIM + k0);
    const bf16x8 a2 = *reinterpret_cast<const bf16x8*>(crow + 32 * DIM + k0);
    const bf16x8 a3 = *reinterpret_cast<const bf16x8*>(crow + 48 * DIM + k0);
    bf16x8 bfrag;
    #pragma unroll
    for (int j = 0; j < 8; ++j) {
      x2 = fmaf(xf[j], xf[j], x2);
      const unsigned u = __float_as_uint(xf[j]);
      bfrag[j] = (short)((u + 0x7FFFu + ((u >> 16) & 1u)) >> 16);
    }
    acc[0] = __builtin_amdgcn_mfma_f32_16x16x32_bf16(a0, bfrag, acc[0], 0, 0, 0);
    acc[1] = __builtin_amdgcn_mfma_f32_16x16x32_bf16(a1, bfrag, acc[1], 0, 0, 0);
    acc[2] = __builtin_amdgcn_mfma_f32_16x16x32_bf16(a2, bfrag, acc[2], 0, 0, 0);
    acc[3] = __builtin_amdgcn_mfma_f32_16x16x32_bf16(a3, bfrag, acc[3], 0, 0, 0);
  }

  x2 += __shfl_xor(x2, 16, 64);
  x2 += __shfl_xor(x2, 32, 64);

  const int col = s0 + (lane & 15);
  #pragma unroll
  for (int t = 0; t < 4; ++t) {
    #pragma unroll
    for (int r = 0; r < 4; ++r) {
      const int cls = t * 16 + (lane >> 4) * 4 + r;
      const float d2 = c2[cls] + x2 - 2.0f * acc[t][r];
      dist[(size_t)cls * N_SAMP + col] = sqrtf(fmaxf(d2, 1e-12f));
    }
  }
}

// ------------------------------------------------- reduction helper (1024-thread block)
__device__ __forceinline__ void redB(float v0, float v2, float v3, float* redf, float* bcast) {
  #pragma unroll
  for (int o = 32; o; o >>= 1) {
    v0 += __shfl_xor(v0, o, 64);
    v2 = fminf(v2, __shfl_xor(v2, o, 64));
    v3 = fmaxf(v3, __shfl_xor(v3, o, 64));
  }
  const int wid = threadIdx.x >> 6;
  if ((threadIdx.x & 63) == 0) { redf[wid] = v0; redf[16 + wid] = v2; redf[32 + wid] = v3; }
  __syncthreads();
  if (threadIdx.x < 16) {
    const int l = threadIdx.x;
    float a0 = redf[l], a2 = redf[16 + l], a3 = redf[32 + l];
    #pragma unroll
    for (int o = 8; o; o >>= 1) {
      a0 += __shfl_xor(a0, o, 64);
      a2 = fminf(a2, __shfl_xor(a2, o, 64));
      a3 = fmaxf(a3, __shfl_xor(a3, o, 64));
    }
    if (l == 0) { bcast[0] = a0; bcast[2] = a2; bcast[3] = a3; }
  }
  __syncthreads();
}

__device__ __forceinline__ int binS(float w, float lo, float sc) {
  int b = (int)((w - lo) * sc);
  b = b < SNBIN - 1 ? b : SNBIN - 1;
  return b > 0 ? b : 0;
}

// exact wave-level sum of `need` smallest among cnt LDS values
__device__ __forceinline__ float wavePeel(const float* buf, int cnt, int need, int lane) {
  float thr = -1e30f, s = 0.f;
  int taken = 0;
  for (int g = 0; g < 64 && taken < need; ++g) {
    float m = 1e30f;
    for (int t = 0; t < 16; ++t) {
      const int idx = lane + t * 64;
      if (idx < cnt) { const float u = buf[idx]; if (u > thr) m = fminf(m, u); }
    }
    #pragma unroll
    for (int o = 32; o; o >>= 1) m = fminf(m, __shfl_xor(m, o, 64));
    int ce = 0;
    for (int t = 0; t < 16; ++t) {
      const int idx = lane + t * 64;
      if (idx < cnt && buf[idx] == m) ++ce;
    }
    #pragma unroll
    for (int o = 32; o; o >>= 1) ce += __shfl_xor(ce, o, 64);
    const int take = (need - taken) < ce ? (need - taken) : ce;
    s += (float)take * m;
    taken += take;
    thr = m;
  }
  return s;
}

// ------------------------------------------------- stateless selection + fused loss
// grid 128: c = bx>>1, role = bx&1
__global__ __launch_bounds__(1024, 2) void k_select4(const float* __restrict__ dist,
                                                     const int* __restrict__ y,
                                                     float* __restrict__ means,
                                                     unsigned* __restrict__ done,
                                                     float* __restrict__ out) {
  __shared__ unsigned bitmap[2048];
  __shared__ unsigned hist[SNBIN];
  __shared__ unsigned wscan[16];
  __shared__ float redf[48];
  __shared__ float bcast[4];
  __shared__ float bbuf[1024];
  __shared__ int bcnt_s, bsel_s;
  __shared__ unsigned strict_s;
  __shared__ float bsum_s;
  __shared__ int lastflag;

  const int tid = threadIdx.x;
  const int lane = tid & 63;
  const int wid = tid >> 6;
  const int c = blockIdx.x >> 1;
  const int role = blockIdx.x & 1;
  const float* __restrict__ row = dist + (size_t)c * N_SAMP;

  if (tid == 0) { bcnt_s = 0; bsel_s = 0; strict_s = 0u; bsum_s = 0.f; lastflag = 0; }

  {
    const int4* __restrict__ y4 = (const int4*)(y + tid * 64);
    unsigned w0 = 0u, w1 = 0u;
    #pragma unroll
    for (int i = 0; i < 8; ++i) {
      const int4 a = y4[i];
      w0 |= (unsigned)(a.x == c) << (i * 4);
      w0 |= (unsigned)(a.y == c) << (i * 4 + 1);
      w0 |= (unsigned)(a.z == c) << (i * 4 + 2);
      w0 |= (unsigned)(a.w == c) << (i * 4 + 3);
    }
    #pragma unroll
    for (int i = 0; i < 8; ++i) {
      const int4 a = y4[8 + i];
      w1 |= (unsigned)(a.x == c) << (i * 4);
      w1 |= (unsigned)(a.y == c) << (i * 4 + 1);
      w1 |= (unsigned)(a.z == c) << (i * 4 + 2);
      w1 |= (unsigned)(a.w == c) << (i * 4 + 3);
    }
    bitmap[tid * 2] = w0;
    bitmap[tid * 2 + 1] = w1;
  }
  __syncthreads();

  float mn = 1e30f, mx = -1e30f;
  #pragma unroll 4
  for (int i = 0; i < 16; ++i) {
    const int base = i * 4096 + tid * 4;
    const float4 v4 = *reinterpret_cast<const float4*>(row + base);
    const unsigned bits = bitmap[base >> 5] >> (base & 31);
    const float vv[4] = {v4.x, v4.y, v4.z, v4.w};
    #pragma unroll
    for (int j = 0; j < 4; ++j) {
      if ((int)((bits >> j) & 1u) != role) {
        const float w = role ? vv[j] : -vv[j];
        mn = fminf(mn, w);
        mx = fmaxf(mx, w);
      }
    }
  }
  redB(0.f, mn, mx, redf, bcast);
  const float lo = bcast[2], hi = bcast[3];
  const bool deg = !(hi > lo);
  float meanval;

  if (deg) {
    meanval = role ? lo : -lo;
  } else {
    const float sc = (float)SNBIN / (hi - lo);
    for (int i = tid; i < SNBIN; i += 1024) hist[i] = 0u;
    __syncthreads();

    #pragma unroll 4
    for (int i = 0; i < 16; ++i) {
      const int base = i * 4096 + tid * 4;
      const float4 v4 = *reinterpret_cast<const float4*>(row + base);
      const unsigned bits = bitmap[base >> 5] >> (base & 31);
      const float vv[4] = {v4.x, v4.y, v4.z, v4.w};
      #pragma unroll
      for (int j = 0; j < 4; ++j) {
        if ((int)((bits >> j) & 1u) != role) {
          const float w = role ? vv[j] : -vv[j];
          atomicAdd(&hist[binS(w, lo, sc)], 1u);
        }
      }
    }
    __syncthreads();

    {
      unsigned b4[4]; unsigned s4 = 0;
      #pragma unroll
      for (int j = 0; j < 4; ++j) { b4[j] = hist[tid * 4 + j]; s4 += b4[j]; }
      unsigned cum = s4;
      #pragma unroll
      for (int d = 1; d < 64; d <<= 1) {
        const unsigned t = (unsigned)__shfl_up((int)cum, d, 64);
        if (lane >= d) cum += t;
      }
      if (lane == 63) wscan[wid] = cum;
      __syncthreads();
      if (tid < 16) {
        unsigned v = wscan[tid];
        #pragma unroll
        for (int d = 1; d < 16; d <<= 1) {
          const unsigned t = (unsigned)__shfl_up((int)v, d, 64);
          if (tid >= d) v += t;
        }
        wscan[tid] = v;
      }
      __syncthreads();
      const unsigned gcum = cum + (wid ? wscan[wid - 1] : 0u);
      const unsigned gprev = gcum - s4;
      if (gcum >= (unsigned)KSEL && gprev < (unsigned)KSEL) {
        unsigned run = gprev;
        #pragma unroll
        for (int j = 0; j < 4; ++j) {
          if (run + b4[j] >= (unsigned)KSEL) { bsel_s = tid * 4 + j; strict_s = run; break; }
          run += b4[j];
        }
      }
      __syncthreads();
    }
    const int B = bsel_s;
    const int need = KSEL - (int)strict_s;

    float ss = 0.f;
    #pragma unroll 4
    for (int i = 0; i < 16; ++i) {
      const int base = i * 4096 + tid * 4;
      const float4 v4 = *reinterpret_cast<const float4*>(row + base);
      const unsigned bits = bitmap[base >> 5] >> (base & 31);
      const float vv[4] = {v4.x, v4.y, v4.z, v4.w};
      #pragma unroll
      for (int j = 0; j < 4; ++j) {
        if ((int)((bits >> j) & 1u) != role) {
          const float w = role ? vv[j] : -vv[j];
          const int b = binS(w, lo, sc);
          if (b < B) ss += w;
          else if (b == B) { const int p = atomicAdd(&bcnt_s, 1); if (p < 1024) bbuf[p] = w; }
        }
      }
    }
    redB(ss, 0.f, 0.f, redf, bcast);
    const float SS = bcast[0];
    const int cnt = bcnt_s;

    if (cnt <= 1024) {
      if (wid == 0) {
        const float s = wavePeel(bbuf, cnt, need, lane);
        if (lane == 0) bsum_s = s;
      }
      __syncthreads();
    } else {
      float thr = -1e30f, accum = 0.f;
      int taken = 0;
      for (int g = 0; g < 64 && taken < need; ++g) {
        float m = 1e30f;
        for (int i = 0; i < 16; ++i) {
          const int base = i * 4096 + tid * 4;
          const float4 v4 = *reinterpret_cast<const float4*>(row + base);
          const unsigned bits = bitmap[base >> 5] >> (base & 31);
          const float vv[4] = {v4.x, v4.y, v4.z, v4.w};
          for (int j = 0; j < 4; ++j) {
            if ((int)((bits >> j) & 1u) != role) {
              const float w = role ? vv[j] : -vv[j];
              if (binS(w, lo, sc) == B && w > thr) m = fminf(m, w);
            }
          }
        }
        redB(0.f, m, 0.f, redf, bcast);
        const float M = bcast[2];
        float ce = 0.f;
        for (int i = 0; i < 16; ++i) {
          const int base = i * 4096 + tid * 4;
          const float4 v4 = *reinterpret_cast<const float4*>(row + base);
          const unsigned bits = bitmap[base >> 5] >> (base & 31);
          const float vv[4] = {v4.x, v4.y, v4.z, v4.w};
          for (int j = 0; j < 4; ++j) {
            if ((int)((bits >> j) & 1u) != role) {
              const float w = role ? vv[j] : -vv[j];
              if (w == M) ce += 1.f;
            }
          }
        }
        redB(ce, 0.f, 0.f, redf, bcast);
        const int CE = (int)bcast[0];
        const int take = (need - taken) < CE ? (need - taken) : CE;
        accum += (float)take * M;
        taken += take;
        thr = M;
      }
      if (tid == 0) bsum_s = accum;
      __syncthreads();
    }

    const float total = SS + bsum_s;
    meanval = role ? total * (1.0f / 64.0f) : -total * (1.0f / 64.0f);
  }

  if (tid == 0) {
    __hip_atomic_store(&means[role * 64 + c], meanval, __ATOMIC_RELAXED, __HIP_MEMORY_SCOPE_AGENT);
    const unsigned old = __hip_atomic_fetch_add(done, 1u, __ATOMIC_ACQ_REL, __HIP_MEMORY_SCOPE_AGENT);
    lastflag = (old == 127u) ? 1 : 0;
  }
  __syncthreads();
  if (lastflag && tid < 64) {
    const float pm = __hip_atomic_load(&means[tid], __ATOMIC_ACQUIRE, __HIP_MEMORY_SCOPE_AGENT);
    const float nm = __hip_atomic_load(&means[64 + tid], __ATOMIC_ACQUIRE, __HIP_MEMORY_SCOPE_AGENT);
    float pc = fmaxf(1.0f + pm - nm, 0.0f);
    #pragma unroll
    for (int o = 32; o; o >>= 1) pc += __shfl_down(pc, o, 64);
    if (tid == 0) out[0] = pc * (1.0f / 4096.0f);
  }
}

// ----------------------------------------------------------------------
extern "C" void kernel_launch(void* const* d_in, const int* in_sizes, int n_in,
                              void* d_out, int out_size, void* d_ws, size_t ws_size,
                              hipStream_t stream) {
  const float* x = (const float*)d_in[0];
  const int* y = (const int*)d_in[1];
  float* out = (float*)d_out;
  char* w = (char*)d_ws;
  int* counts          = (int*)(w + OFF_COUNTS);
  float* csum          = (float*)(w + OFF_CSUM);
  unsigned short* cenb = (unsigned short*)(w + OFF_CENTERS);
  float* c2            = (float*)(w + OFF_C2);
  float* means         = (float*)(w + OFF_MEANS);
  unsigned* done       = (unsigned*)(w + OFF_DONE);
  float* dist          = (float*)(w + OFF_DIST);

  hipLaunchKernelGGL(k_init, dim3(64), dim3(256), 0, stream, counts, csum, done);
  hipLaunchKernelGGL(k_class_sums, dim3(1024), dim3(256), 0, stream, x, y, csum, counts);
  hipLaunchKernelGGL(k_centers, dim3(64), dim3(64), 0, stream, csum, counts, cenb, c2);
  hipLaunchKernelGGL(k_dist_g, dim3(N_SAMP / 128), dim3(512), 0, stream, x, cenb, c2, dist);
  hipLaunchKernelGGL(k_select4, dim3(128), dim3(1024), 0, stream, dist, y, means, done, out);
}

// Round 10
// 101.949 us; speedup vs baseline: 1.2179x; 1.2179x over previous
//
#include <hip/hip_runtime.h>
#include <hip/hip_bf16.h>
#include <math.h>

#define N_SAMP 65536
#define DIM    512
#define NCLS   64
#define KSEL   64
#define SNBIN  4096

// workspace layout (bytes)
#define OFF_COUNTS   0u          // 64 i32
#define OFF_CSUM     256u        // 64*512 f32 -> 131328
#define OFF_CENTERS  131328u     // cenb 64*512 bf16 -> 196864
#define OFF_C2       196864u     // 64 f32 -> 197120
#define OFF_MEANS    197120u     // 128 f32 -> 197632
#define OFF_DONE     197632u     // 1 u32
#define OFF_DIST     262144u     // 64*65536 f32 -> 17039360

typedef __attribute__((ext_vector_type(8))) short bf16x8;
typedef __attribute__((ext_vector_type(4))) float f32x4;

__device__ __forceinline__ unsigned short f2bf_rne(float f) {
  const unsigned u = __float_as_uint(f);
  return (unsigned short)((u + 0x7FFFu + ((u >> 16) & 1u)) >> 16);
}

// ---------------------------------------------------------------- init
__global__ __launch_bounds__(256) void k_init(int* __restrict__ counts,
                                              float* __restrict__ csum,
                                              unsigned* __restrict__ done) {
  const int i = blockIdx.x * 256 + threadIdx.x;
  const int stride = gridDim.x * 256;
  if (i < NCLS) counts[i] = 0;
  if (i == 0) *done = 0u;
  for (int j = i; j < NCLS * DIM; j += stride) csum[j] = 0.f;
}

// ------------------------------------------------- class partial sums (proven R4 form)
__global__ __launch_bounds__(256) void k_class_sums(const float* __restrict__ x,
                                                    const int* __restrict__ y,
                                                    float* __restrict__ csum,
                                                    int* __restrict__ counts) {
  __shared__ int list[4096];
  __shared__ int lcnt;
  const int c  = blockIdx.x >> 4;
  const int r0 = (blockIdx.x & 15) * 4096;
  const int tid = threadIdx.x;
  if (tid == 0) lcnt = 0;
  __syncthreads();
  for (int i = tid; i < 4096; i += 256) {
    if (y[r0 + i] == c) { int p = atomicAdd(&lcnt, 1); list[p] = r0 + i; }
  }
  __syncthreads();
  const int n = lcnt;
  const int dbase = (tid >> 6) * 128 + (tid & 63) * 2;
  float a0 = 0.f, a1 = 0.f, b0 = 0.f, b1 = 0.f;
  int i = 0;
  for (; i + 2 <= n; i += 2) {
    const float* p0 = x + (size_t)list[i] * DIM + dbase;
    const float* p1 = x + (size_t)list[i + 1] * DIM + dbase;
    a0 += p0[0]; a1 += p0[1];
    b0 += p1[0]; b1 += p1[1];
  }
  if (i < n) { const float* p0 = x + (size_t)list[i] * DIM + dbase; a0 += p0[0]; a1 += p0[1]; }
  a0 += b0; a1 += b1;
  atomicAdd(&csum[c * DIM + dbase], a0);
  atomicAdd(&csum[c * DIM + dbase + 1], a1);
  if (tid == 0) atomicAdd(&counts[c], n);
}

// ------------------------------------------------- finalize centers (bf16) + c2 (f32)
__global__ __launch_bounds__(64) void k_centers(const float* __restrict__ csum,
                                                const int* __restrict__ counts,
                                                unsigned short* __restrict__ cenb,
                                                float* __restrict__ c2) {
  const int c = blockIdx.x, l = threadIdx.x;
  const float inv = 1.0f / (float)counts[c];
  float ss = 0.f;
  #pragma unroll
  for (int j = 0; j < 8; ++j) {
    int d = j * 64 + l;
    float v = csum[c * DIM + d] * inv;
    cenb[c * DIM + d] = f2bf_rne(v);
    ss += v * v;
  }
  #pragma unroll
  for (int o = 32; o; o >>= 1) ss += __shfl_down(ss, o, 64);
  if (l == 0) c2[c] = ss;
}

// ------------------------------------------------- distances via bf16 MFMA (proven R4 LDS form
// + packed cvt). 512 blocks x 512 threads (8 waves, 16 samples/wave, all 64 classes).
#define CSTR 520
__global__ __launch_bounds__(512, 4) void k_dist_mfma(const float* __restrict__ x,
                                                      const unsigned short* __restrict__ cenb,
                                                      const float* __restrict__ c2,
                                                      float* __restrict__ dist) {
  __shared__ unsigned short cenS[NCLS * CSTR];   // 66560 B -> 2 blocks/CU
  __shared__ float c2s[NCLS];

  const int tid = threadIdx.x;
  const int wave = tid >> 6;
  const int lane = tid & 63;
  const int s0 = blockIdx.x * 128 + wave * 16;
  const int samp = s0 + (lane & 15);
  const int kg = lane >> 4;

  for (int q = tid; q < 4096; q += 512) {
    const int row = q >> 6, cc = q & 63;
    const uint4 v = *reinterpret_cast<const uint4*>(cenb + row * DIM + cc * 8);
    *reinterpret_cast<uint4*>(&cenS[row * CSTR + cc * 8]) = v;
  }
  if (tid < NCLS) c2s[tid] = c2[tid];
  __syncthreads();

  f32x4 acc[4] = {f32x4{0,0,0,0}, f32x4{0,0,0,0}, f32x4{0,0,0,0}, f32x4{0,0,0,0}};
  float x2 = 0.f;
  const float* __restrict__ xrow = x + (size_t)samp * DIM + kg * 8;
  const int arow = lane & 15;

  union BB { bf16x8 v; __hip_bfloat162 h[4]; };

  #pragma unroll 4
  for (int s = 0; s < 16; ++s) {
    const int k0 = s * 32;
    float xf[8];
    *reinterpret_cast<float4*>(&xf[0]) = *reinterpret_cast<const float4*>(xrow + k0);
    *reinterpret_cast<float4*>(&xf[4]) = *reinterpret_cast<const float4*>(xrow + k0 + 4);
    BB bb;
    bb.h[0] = __float22bfloat162_rn(make_float2(xf[0], xf[1]));
    bb.h[1] = __float22bfloat162_rn(make_float2(xf[2], xf[3]));
    bb.h[2] = __float22bfloat162_rn(make_float2(xf[4], xf[5]));
    bb.h[3] = __float22bfloat162_rn(make_float2(xf[6], xf[7]));
    #pragma unroll
    for (int j = 0; j < 8; ++j) x2 = fmaf(xf[j], xf[j], x2);
    const int kidx = k0 + kg * 8;
    const bf16x8 a0 = *reinterpret_cast<const bf16x8*>(&cenS[(arow +  0) * CSTR + kidx]);
    const bf16x8 a1 = *reinterpret_cast<const bf16x8*>(&cenS[(arow + 16) * CSTR + kidx]);
    const bf16x8 a2 = *reinterpret_cast<const bf16x8*>(&cenS[(arow + 32) * CSTR + kidx]);
    const bf16x8 a3 = *reinterpret_cast<const bf16x8*>(&cenS[(arow + 48) * CSTR + kidx]);
    acc[0] = __builtin_amdgcn_mfma_f32_16x16x32_bf16(a0, bb.v, acc[0], 0, 0, 0);
    acc[1] = __builtin_amdgcn_mfma_f32_16x16x32_bf16(a1, bb.v, acc[1], 0, 0, 0);
    acc[2] = __builtin_amdgcn_mfma_f32_16x16x32_bf16(a2, bb.v, acc[2], 0, 0, 0);
    acc[3] = __builtin_amdgcn_mfma_f32_16x16x32_bf16(a3, bb.v, acc[3], 0, 0, 0);
  }

  x2 += __shfl_xor(x2, 16, 64);
  x2 += __shfl_xor(x2, 32, 64);

  const int col = s0 + (lane & 15);
  #pragma unroll
  for (int t = 0; t < 4; ++t) {
    #pragma unroll
    for (int r = 0; r < 4; ++r) {
      const int cls = t * 16 + (lane >> 4) * 4 + r;
      const float d2 = c2s[cls] + x2 - 2.0f * acc[t][r];
      dist[(size_t)cls * N_SAMP + col] = sqrtf(fmaxf(d2, 1e-12f));
    }
  }
}

// ------------------------------------------------- reduction helper (1024-thread block)
__device__ __forceinline__ void redB(float v0, float v2, float v3, float* redf, float* bcast) {
  #pragma unroll
  for (int o = 32; o; o >>= 1) {
    v0 += __shfl_xor(v0, o, 64);
    v2 = fminf(v2, __shfl_xor(v2, o, 64));
    v3 = fmaxf(v3, __shfl_xor(v3, o, 64));
  }
  const int wid = threadIdx.x >> 6;
  if ((threadIdx.x & 63) == 0) { redf[wid] = v0; redf[16 + wid] = v2; redf[32 + wid] = v3; }
  __syncthreads();
  if (threadIdx.x < 16) {
    const int l = threadIdx.x;
    float a0 = redf[l], a2 = redf[16 + l], a3 = redf[32 + l];
    #pragma unroll
    for (int o = 8; o; o >>= 1) {
      a0 += __shfl_xor(a0, o, 64);
      a2 = fminf(a2, __shfl_xor(a2, o, 64));
      a3 = fmaxf(a3, __shfl_xor(a3, o, 64));
    }
    if (l == 0) { bcast[0] = a0; bcast[2] = a2; bcast[3] = a3; }
  }
  __syncthreads();
}

__device__ __forceinline__ int binS(float w, float lo, float sc) {
  int b = (int)((w - lo) * sc);
  b = b < SNBIN - 1 ? b : SNBIN - 1;
  return b > 0 ? b : 0;
}

// exact wave-level sum of `need` smallest among cnt LDS values
__device__ __forceinline__ float wavePeel(const float* buf, int cnt, int need, int lane) {
  float thr = -1e30f, s = 0.f;
  int taken = 0;
  for (int g = 0; g < 64 && taken < need; ++g) {
    float m = 1e30f;
    for (int t = 0; t < 16; ++t) {
      const int idx = lane + t * 64;
      if (idx < cnt) { const float u = buf[idx]; if (u > thr) m = fminf(m, u); }
    }
    #pragma unroll
    for (int o = 32; o; o >>= 1) m = fminf(m, __shfl_xor(m, o, 64));
    int ce = 0;
    for (int t = 0; t < 16; ++t) {
      const int idx = lane + t * 64;
      if (idx < cnt && buf[idx] == m) ++ce;
    }
    #pragma unroll
    for (int o = 32; o; o >>= 1) ce += __shfl_xor(ce, o, 64);
    const int take = (need - taken) < ce ? (need - taken) : ce;
    s += (float)take * m;
    taken += take;
    thr = m;
  }
  return s;
}

// ------------------------------------------------- stateless selection + fused loss (proven)
// grid 128: c = bx>>1, role = bx&1
__global__ __launch_bounds__(1024, 2) void k_select4(const float* __restrict__ dist,
                                                     const int* __restrict__ y,
                                                     float* __restrict__ means,
                                                     unsigned* __restrict__ done,
                                                     float* __restrict__ out) {
  __shared__ unsigned bitmap[2048];
  __shared__ unsigned hist[SNBIN];
  __shared__ unsigned wscan[16];
  __shared__ float redf[48];
  __shared__ float bcast[4];
  __shared__ float bbuf[1024];
  __shared__ int bcnt_s, bsel_s;
  __shared__ unsigned strict_s;
  __shared__ float bsum_s;
  __shared__ int lastflag;

  const int tid = threadIdx.x;
  const int lane = tid & 63;
  const int wid = tid >> 6;
  const int c = blockIdx.x >> 1;
  const int role = blockIdx.x & 1;
  const float* __restrict__ row = dist + (size_t)c * N_SAMP;

  if (tid == 0) { bcnt_s = 0; bsel_s = 0; strict_s = 0u; bsum_s = 0.f; lastflag = 0; }

  {
    const int4* __restrict__ y4 = (const int4*)(y + tid * 64);
    unsigned w0 = 0u, w1 = 0u;
    #pragma unroll
    for (int i = 0; i < 8; ++i) {
      const int4 a = y4[i];
      w0 |= (unsigned)(a.x == c) << (i * 4);
      w0 |= (unsigned)(a.y == c) << (i * 4 + 1);
      w0 |= (unsigned)(a.z == c) << (i * 4 + 2);
      w0 |= (unsigned)(a.w == c) << (i * 4 + 3);
    }
    #pragma unroll
    for (int i = 0; i < 8; ++i) {
      const int4 a = y4[8 + i];
      w1 |= (unsigned)(a.x == c) << (i * 4);
      w1 |= (unsigned)(a.y == c) << (i * 4 + 1);
      w1 |= (unsigned)(a.z == c) << (i * 4 + 2);
      w1 |= (unsigned)(a.w == c) << (i * 4 + 3);
    }
    bitmap[tid * 2] = w0;
    bitmap[tid * 2 + 1] = w1;
  }
  __syncthreads();

  float mn = 1e30f, mx = -1e30f;
  #pragma unroll 4
  for (int i = 0; i < 16; ++i) {
    const int base = i * 4096 + tid * 4;
    const float4 v4 = *reinterpret_cast<const float4*>(row + base);
    const unsigned bits = bitmap[base >> 5] >> (base & 31);
    const float vv[4] = {v4.x, v4.y, v4.z, v4.w};
    #pragma unroll
    for (int j = 0; j < 4; ++j) {
      if ((int)((bits >> j) & 1u) != role) {
        const float w = role ? vv[j] : -vv[j];
        mn = fminf(mn, w);
        mx = fmaxf(mx, w);
      }
    }
  }
  redB(0.f, mn, mx, redf, bcast);
  const float lo = bcast[2], hi = bcast[3];
  const bool deg = !(hi > lo);
  float meanval;

  if (deg) {
    meanval = role ? lo : -lo;
  } else {
    const float sc = (float)SNBIN / (hi - lo);
    for (int i = tid; i < SNBIN; i += 1024) hist[i] = 0u;
    __syncthreads();

    #pragma unroll 4
    for (int i = 0; i < 16; ++i) {
      const int base = i * 4096 + tid * 4;
      const float4 v4 = *reinterpret_cast<const float4*>(row + base);
      const unsigned bits = bitmap[base >> 5] >> (base & 31);
      const float vv[4] = {v4.x, v4.y, v4.z, v4.w};
      #pragma unroll
      for (int j = 0; j < 4; ++j) {
        if ((int)((bits >> j) & 1u) != role) {
          const float w = role ? vv[j] : -vv[j];
          atomicAdd(&hist[binS(w, lo, sc)], 1u);
        }
      }
    }
    __syncthreads();

    {
      unsigned b4[4]; unsigned s4 = 0;
      #pragma unroll
      for (int j = 0; j < 4; ++j) { b4[j] = hist[tid * 4 + j]; s4 += b4[j]; }
      unsigned cum = s4;
      #pragma unroll
      for (int d = 1; d < 64; d <<= 1) {
        const unsigned t = (unsigned)__shfl_up((int)cum, d, 64);
        if (lane >= d) cum += t;
      }
      if (lane == 63) wscan[wid] = cum;
      __syncthreads();
      if (tid < 16) {
        unsigned v = wscan[tid];
        #pragma unroll
        for (int d = 1; d < 16; d <<= 1) {
          const unsigned t = (unsigned)__shfl_up((int)v, d, 64);
          if (tid >= d) v += t;
        }
        wscan[tid] = v;
      }
      __syncthreads();
      const unsigned gcum = cum + (wid ? wscan[wid - 1] : 0u);
      const unsigned gprev = gcum - s4;
      if (gcum >= (unsigned)KSEL && gprev < (unsigned)KSEL) {
        unsigned run = gprev;
        #pragma unroll
        for (int j = 0; j < 4; ++j) {
          if (run + b4[j] >= (unsigned)KSEL) { bsel_s = tid * 4 + j; strict_s = run; break; }
          run += b4[j];
        }
      }
      __syncthreads();
    }
    const int B = bsel_s;
    const int need = KSEL - (int)strict_s;

    float ss = 0.f;
    #pragma unroll 4
    for (int i = 0; i < 16; ++i) {
      const int base = i * 4096 + tid * 4;
      const float4 v4 = *reinterpret_cast<const float4*>(row + base);
      const unsigned bits = bitmap[base >> 5] >> (base & 31);
      const float vv[4] = {v4.x, v4.y, v4.z, v4.w};
      #pragma unroll
      for (int j = 0; j < 4; ++j) {
        if ((int)((bits >> j) & 1u) != role) {
          const float w = role ? vv[j] : -vv[j];
          const int b = binS(w, lo, sc);
          if (b < B) ss += w;
          else if (b == B) { const int p = atomicAdd(&bcnt_s, 1); if (p < 1024) bbuf[p] = w; }
        }
      }
    }
    redB(ss, 0.f, 0.f, redf, bcast);
    const float SS = bcast[0];
    const int cnt = bcnt_s;

    if (cnt <= 1024) {
      if (wid == 0) {
        const float s = wavePeel(bbuf, cnt, need, lane);
        if (lane == 0) bsum_s = s;
      }
      __syncthreads();
    } else {
      float thr = -1e30f, accum = 0.f;
      int taken = 0;
      for (int g = 0; g < 64 && taken < need; ++g) {
        float m = 1e30f;
        for (int i = 0; i < 16; ++i) {
          const int base = i * 4096 + tid * 4;
          const float4 v4 = *reinterpret_cast<const float4*>(row + base);
          const unsigned bits = bitmap[base >> 5] >> (base & 31);
          const float vv[4] = {v4.x, v4.y, v4.z, v4.w};
          for (int j = 0; j < 4; ++j) {
            if ((int)((bits >> j) & 1u) != role) {
              const float w = role ? vv[j] : -vv[j];
              if (binS(w, lo, sc) == B && w > thr) m = fminf(m, w);
            }
          }
        }
        redB(0.f, m, 0.f, redf, bcast);
        const float M = bcast[2];
        float ce = 0.f;
        for (int i = 0; i < 16; ++i) {
          const int base = i * 4096 + tid * 4;
          const float4 v4 = *reinterpret_cast<const float4*>(row + base);
          const unsigned bits = bitmap[base >> 5] >> (base & 31);
          const float vv[4] = {v4.x, v4.y, v4.z, v4.w};
          for (int j = 0; j < 4; ++j) {
            if ((int)((bits >> j) & 1u) != role) {
              const float w = role ? vv[j] : -vv[j];
              if (w == M) ce += 1.f;
            }
          }
        }
        redB(ce, 0.f, 0.f, redf, bcast);
        const int CE = (int)bcast[0];
        const int take = (need - taken) < CE ? (need - taken) : CE;
        accum += (float)take * M;
        taken += take;
        thr = M;
      }
      if (tid == 0) bsum_s = accum;
      __syncthreads();
    }

    const float total = SS + bsum_s;
    meanval = role ? total * (1.0f / 64.0f) : -total * (1.0f / 64.0f);
  }

  if (tid == 0) {
    __hip_atomic_store(&means[role * 64 + c], meanval, __ATOMIC_RELAXED, __HIP_MEMORY_SCOPE_AGENT);
    const unsigned old = __hip_atomic_fetch_add(done, 1u, __ATOMIC_ACQ_REL, __HIP_MEMORY_SCOPE_AGENT);
    lastflag = (old == 127u) ? 1 : 0;
  }
  __syncthreads();
  if (lastflag && tid < 64) {
    const float pm = __hip_atomic_load(&means[tid], __ATOMIC_ACQUIRE, __HIP_MEMORY_SCOPE_AGENT);
    const float nm = __hip_atomic_load(&means[64 + tid], __ATOMIC_ACQUIRE, __HIP_MEMORY_SCOPE_AGENT);
    float pc = fmaxf(1.0f + pm - nm, 0.0f);
    #pragma unroll
    for (int o = 32; o; o >>= 1) pc += __shfl_down(pc, o, 64);
    if (tid == 0) out[0] = pc * (1.0f / 4096.0f);
  }
}

// ----------------------------------------------------------------------
extern "C" void kernel_launch(void* const* d_in, const int* in_sizes, int n_in,
                              void* d_out, int out_size, void* d_ws, size_t ws_size,
                              hipStream_t stream) {
  const float* x = (const float*)d_in[0];
  const int* y = (const int*)d_in[1];
  float* out = (float*)d_out;
  char* w = (char*)d_ws;
  int* counts          = (int*)(w + OFF_COUNTS);
  float* csum          = (float*)(w + OFF_CSUM);
  unsigned short* cenb = (unsigned short*)(w + OFF_CENTERS);
  float* c2            = (float*)(w + OFF_C2);
  float* means         = (float*)(w + OFF_MEANS);
  unsigned* done       = (unsigned*)(w + OFF_DONE);
  float* dist          = (float*)(w + OFF_DIST);

  hipLaunchKernelGGL(k_init, dim3(64), dim3(256), 0, stream, counts, csum, done);
  hipLaunchKernelGGL(k_class_sums, dim3(1024), dim3(256), 0, stream, x, y, csum, counts);
  hipLaunchKernelGGL(k_centers, dim3(64), dim3(64), 0, stream, csum, counts, cenb, c2);
  hipLaunchKernelGGL(k_dist_mfma, dim3(N_SAMP / 128), dim3(512), 0, stream, x, cenb, c2, dist);
  hipLaunchKernelGGL(k_select4, dim3(128), dim3(1024), 0, stream, dist, y, means, done, out);
}